// Round 1
// baseline (29.235 us; speedup 1.0000x reference)
//
#include <hip/hip_runtime.h>

#define NB 16384
#define KC 64
#define NS 32
#define FD 64

__global__ __launch_bounds__(256) void intra_agg_kernel(
    const float* __restrict__ features,
    const float* __restrict__ center_scores,
    const float* __restrict__ neigh_scores,
    const int*   __restrict__ neighs,
    float*       __restrict__ out)
{
    const int wave = threadIdx.x >> 6;   // 0..3  (one 64-lane wave per row)
    const int lane = threadIdx.x & 63;
    const int row  = blockIdx.x * 4 + wave;

    __shared__ float dval[4][KC];
    __shared__ int   selid[4][NS];

    // ---- phase 1: per-candidate distance, stable rank, select 32 smallest ----
    const float c  = center_scores[row];
    const float ns = neigh_scores[(long)row * KC + lane];
    const float d  = fabsf(c - ns);
    dval[wave][lane] = d;
    __syncthreads();

    int rank = 0;
    #pragma unroll
    for (int j = 0; j < KC; ++j) {
        const float dj = dval[wave][j];           // broadcast read: conflict-free
        rank += (dj < d) || (dj == d && j < lane); // top_k stable tie-break
    }
    if (rank < NS) {
        selid[wave][rank] = neighs[(long)row * KC + lane];
        // samp_scores output region starts after to_feats [NB, FD]
        out[(long)NB * FD + (long)row * NS + rank] = d;
    }
    __syncthreads();

    // ---- phase 2: gather 32 feature rows, mean + relu ----
    float acc = 0.0f;
    #pragma unroll
    for (int s = 0; s < NS; ++s) {
        const long node = selid[wave][s];
        acc += features[node * FD + lane];        // 64 lanes x 4B = 256B coalesced
    }
    out[(long)row * FD + lane] = fmaxf(acc * (1.0f / NS), 0.0f);
}

extern "C" void kernel_launch(void* const* d_in, const int* in_sizes, int n_in,
                              void* d_out, int out_size, void* d_ws, size_t ws_size,
                              hipStream_t stream) {
    const float* features      = (const float*)d_in[0];
    const float* center_scores = (const float*)d_in[1];
    const float* neigh_scores  = (const float*)d_in[2];
    const int*   neighs        = (const int*)d_in[3];
    // d_in[4] = num_sample scalar (fixed at 32, hardcoded as NS)
    float* out = (float*)d_out;

    intra_agg_kernel<<<NB / 4, 256, 0, stream>>>(
        features, center_scores, neigh_scores, neighs, out);
}